// Round 7
// baseline (734.126 us; speedup 1.0000x reference)
//
#include <hip/hip_runtime.h>
#include <hip/hip_bf16.h>
#include <math.h>

typedef __attribute__((ext_vector_type(8))) short short8;
typedef __attribute__((ext_vector_type(4))) short short4v;
typedef __attribute__((ext_vector_type(4))) float floatx4;
typedef unsigned short ushort_t;
typedef unsigned int uint_t;

__device__ __forceinline__ ushort_t f2bf(float x) {   // RNE f32 -> bf16
    uint_t u = __float_as_uint(x);
    uint_t r = (u + 0x7fffu + ((u >> 16) & 1u)) >> 16;
    return (ushort_t)r;
}
// HW-packed RNE conversion: 2 floats -> packed bf16x2 (v_cvt_pk_bf16_f32)
__device__ __forceinline__ short4v pack4(float a, float b, float c, float d) {
    union { __hip_bfloat162 h; uint_t u; } lo, hi;
    lo.h = __float22bfloat162_rn(make_float2(a, b));
    hi.h = __float22bfloat162_rn(make_float2(c, d));
    short4v r;
    r[0] = (short)(lo.u & 0xffffu); r[1] = (short)(lo.u >> 16);
    r[2] = (short)(hi.u & 0xffffu); r[3] = (short)(hi.u >> 16);
    return r;
}
__device__ __forceinline__ short8 pack8(float4 v0, float4 v1) {
    short4v lo = pack4(v0.x, v0.y, v0.z, v0.w);
    short4v hi = pack4(v1.x, v1.y, v1.z, v1.w);
    short8 pk;
    pk[0] = lo[0]; pk[1] = lo[1]; pk[2] = lo[2]; pk[3] = lo[3];
    pk[4] = hi[0]; pk[5] = hi[1]; pk[6] = hi[2]; pk[7] = hi[3];
    return pk;
}

// ---------------- prep: weight tiling (W1/W2/W3) + partial GAP -------------
__global__ void prep_all(const float* __restrict__ W1a, const float* __restrict__ W2a,
                         const float* __restrict__ W1b, const float* __restrict__ W2b,
                         const float* __restrict__ W3a, const float* __restrict__ W3b,
                         ushort_t* __restrict__ wt, ushort_t* __restrict__ w3t,
                         const float* __restrict__ f4, float* __restrict__ part) {
    __shared__ float4 red[256];
    int bi = blockIdx.x, t = threadIdx.x;
    if (bi < 432) {
        int i = bi * 256 + t;
        const float* W; int off; int C;
        if (i < 18432)      { W = W1a; off = i;         C = 32; }
        else if (i < 55296) { W = W2a; off = i - 18432; C = 64; }
        else if (i < 73728) { W = W1b; off = i - 55296; C = 32; }
        else                { W = W2b; off = i - 73728; C = 64; }
        int pt = C * 64;
        int tap = off / pt, rem = off - tap * pt;
        int k4 = rem >> 9, rem2 = rem & 511;
        int co = rem2 >> 3, j = rem2 & 7;
        int ci = k4 * 8 + j;
        wt[i] = f2bf(W[(size_t)(tap * C + ci) * 64 + co]);
    } else if (bi < 648) {
        int i = (bi - 432) * 256 + t;          // [0, 55296)
        int branch = i / 27648; int r = i - branch * 27648;
        int cls = r / 9216; int r2 = r - cls * 9216;
        int t2 = r2 >> 9; int r3 = r2 & 511;
        int qq = r3 >> 7; int r4 = r3 & 127;
        int ch = r4 >> 3; int j = r4 & 7;
        int tap = t2 >> 1, kh = t2 & 1;
        int ci = kh * 32 + qq * 8 + j;
        int NCH = branch ? 1 : 2, C3 = branch ? 3 : 6;
        const float* W3 = branch ? W3b : W3a;
        ushort_t v = 0;
        if (ch < NCH) v = f2bf(W3[(size_t)(tap * 64 + ci) * C3 + cls * NCH + ch]);
        w3t[i] = v;
    } else {
        int g = bi - 648;
        int c = g & 7, b = g >> 3;
        int ci4 = t & 63, po = t >> 6;
        const float* f = f4 + ((size_t)b * 1024 + c * 128) * 256;
        float4 s = {0, 0, 0, 0};
        for (int i = 0; i < 32; ++i) {
            float4 v = *(const float4*)&f[(size_t)(i * 4 + po) * 256 + ci4 * 4];
            s.x += v.x; s.y += v.y; s.z += v.z; s.w += v.w;
        }
        red[t] = s;
        __syncthreads();
        if (t < 64) {
            float4 a = red[t], b2 = red[64 + t], c2 = red[128 + t], d2 = red[192 + t];
            float4 gg;
            gg.x = a.x + b2.x + c2.x + d2.x;
            gg.y = a.y + b2.y + c2.y + d2.y;
            gg.z = a.z + b2.z + c2.z + d2.z;
            gg.w = a.w + b2.w + c2.w + d2.w;
            *(float4*)&part[((b * 8 + c) << 8) + t * 4] = gg;
        }
    }
}

// ---------------- classifier finish: MLP + softmax + argmax ----------------
__global__ void cls_finish(const float* __restrict__ part,
                           const float* __restrict__ Wc1, const float* __restrict__ bc1,
                           const float* __restrict__ Wc2, const float* __restrict__ bc2,
                           const float* __restrict__ Wc3, const float* __restrict__ bc3,
                           float* __restrict__ pred_out, int* __restrict__ cls_out) {
    int b = blockIdx.x;
    int t = threadIdx.x;                       // 256 threads
    __shared__ float gap[256];
    __shared__ float z1[128];
    __shared__ float z2[128];
    __shared__ float lg[3];
    float s = 0.f;
    for (int c = 0; c < 8; ++c) s += part[((b * 8 + c) << 8) + t];
    gap[t] = s * (1.0f / 1024.0f);
    __syncthreads();
    if (t < 128) {
        float a = bc1[t];
        for (int i = 0; i < 256; ++i) a += gap[i] * Wc1[i * 128 + t];
        z1[t] = fmaxf(a, 0.f);
    }
    __syncthreads();
    if (t < 128) {
        float a = bc2[t];
        for (int i = 0; i < 128; ++i) a += z1[i] * Wc2[i * 128 + t];
        z2[t] = fmaxf(a, 0.f);
    }
    __syncthreads();
    if (t < 3) {
        float a = bc3[t];
        for (int i = 0; i < 128; ++i) a += z2[i] * Wc3[i * 3 + t];
        lg[t] = a;
    }
    __syncthreads();
    if (t == 0) {
        float m = fmaxf(lg[0], fmaxf(lg[1], lg[2]));
        float e0 = expf(lg[0] - m), e1 = expf(lg[1] - m), e2 = expf(lg[2] - m);
        float ssum = e0 + e1 + e2;
        pred_out[b * 3 + 0] = e0 / ssum;
        pred_out[b * 3 + 1] = e1 / ssum;
        pred_out[b * 3 + 2] = e2 / ssum;
        int idx = 0; float best = lg[0];
        if (lg[1] > best) { best = lg[1]; idx = 1; }
        if (lg[2] > best) { best = lg[2]; idx = 2; }
        cls_out[b] = idx;
    }
}

// ---------------- fused MFMA conv branch (both branches, grid.z) -----------
// R6 structure + two zero-structural-risk deltas:
//   (1) #pragma unroll 3 on conv1/conv2 loops: 3-deep effective A-prefetch
//       (hides ~200cy L1 latency that a 1-tap window cannot) + renames away
//       2/3 of the now<-next rotation movs
//   (2) s_setprio(1) around MFMA clusters (3 independent blocks/CU at
//       different phases -> arbitration pays, m191 regime)
// LDS (ushort):
//   x0  [4 ks x 2600]           : [0, 10400)
//   h1  [8 ks x 2056]           : [10400, 26848)
//   h2  [8 kq][196 px][8 ch]    : [0, 12544)
//   SF  float partials 1152     : floats [6272,7424)
// Total 53696 B -> 3 blocks/CU.
#define X0_E 0
#define X0_KS 2600
#define H1_E 10400
#define H1_KS 2056
#define H2_E 0
#define H2_KQ 1568
#define SF_F 6272
#define LDS_E 26848

__global__ __launch_bounds__(256, 3)
void fused_branch(const float* __restrict__ x0,
                  const ushort_t* __restrict__ W1o_t, const ushort_t* __restrict__ W2o_t,
                  const ushort_t* __restrict__ W1w_t, const ushort_t* __restrict__ W2w_t,
                  const ushort_t* __restrict__ w3t,
                  const float* __restrict__ bo1, const float* __restrict__ bo2,
                  const float* __restrict__ bw1, const float* __restrict__ bw2,
                  const float* __restrict__ bo3, const float* __restrict__ bw3,
                  const int* __restrict__ clsp,
                  float* __restrict__ off_out, float* __restrict__ w_out) {
    __shared__ __align__(16) ushort_t lds[LDS_E];
    float* ldsf = (float*)lds;
    const int t = threadIdx.x;
    const int b = blockIdx.y;
    const int z = blockIdx.z;
    const ushort_t* W1t = z ? W1w_t : W1o_t;
    const ushort_t* W2t = z ? W2w_t : W2o_t;
    const ushort_t* W3T = w3t + z * 27648;
    const float* B1 = z ? bw1 : bo1;
    const float* B2 = z ? bw2 : bo2;
    const float* B3 = z ? bw3 : bo3;
    float* outp = z ? w_out : off_out;
    const int NCH = z ? 1 : 2;

    const int tileY = blockIdx.x / 43, tileX = blockIdx.x - tileY * 43;
    const int ty0 = tileY * 12, tx0 = tileX * 12;
    const bool edge = (tileY == 0) | (tileY == 42) | (tileX == 0) | (tileX == 42);
    const int lane = t & 63, wave = t >> 6;
    const int m = lane & 15, q = lane >> 4;
    const int cls = clsp[b];

    // ---- stage x0 (18x18x32 fp32 -> bf16 [4 ks][324 px][8]), pixel-major --
    for (int pix = t; pix < 324; pix += 256) {
        int py = pix / 18, px = pix - py * 18;
        int gy = ty0 - 3 + py, gx = tx0 - 3 + px;
        ushort_t* dst = &lds[X0_E + pix * 8];
        if (!edge || ((uint_t)gy < 512u && (uint_t)gx < 512u)) {
            const float* xp = x0 + (((size_t)b * 512 + gy) * 512 + gx) * 32;
#pragma unroll
            for (int qq = 0; qq < 4; ++qq)
                *(short8*)&dst[qq * X0_KS] =
                    pack8(*(const float4*)(xp + qq * 8), *(const float4*)(xp + qq * 8 + 4));
        } else {
            short8 zz = {0, 0, 0, 0, 0, 0, 0, 0};
#pragma unroll
            for (int qq = 0; qq < 4; ++qq)
                *(short8*)&dst[qq * X0_KS] = zz;
        }
    }
    __syncthreads();                                   // (1)

    // ================= conv1: h1(16x16x64), A from global =================
    {
        floatx4 acc[4][4];
#pragma unroll
        for (int mi = 0; mi < 4; ++mi) {
            float4 bb = *(const float4*)&B1[mi * 16 + q * 4];   // bias as C-init
            floatx4 ib = (floatx4){bb.x, bb.y, bb.z, bb.w};
#pragma unroll
            for (int n = 0; n < 4; ++n) acc[mi][n] = ib;
        }
        const int wsel = q * 512 + m * 8;
        short8 Anow[4], Bnow[4];
#pragma unroll
        for (int mi = 0; mi < 4; ++mi)
            Anow[mi] = *(const short8*)&W1t[wsel + mi * 128];
#pragma unroll
        for (int n = 0; n < 4; ++n)                    // tap 0: dy=0, dx=0
            Bnow[n] = *(const short8*)&lds[X0_E + q * X0_KS + ((n * 4 + wave) * 18 + m) * 8];

#pragma unroll 3
        for (int tap = 0; tap < 9; ++tap) {
            int tn = tap < 8 ? tap + 1 : 8;
            int dyn = tn / 3, dxn = tn - dyn * 3;
            short8 Anext[4];
#pragma unroll
            for (int mi = 0; mi < 4; ++mi)
                Anext[mi] = *(const short8*)&W1t[tn * 2048 + wsel + mi * 128];
            short8 Bnext[4];
#pragma unroll
            for (int n = 0; n < 4; ++n)
                Bnext[n] = *(const short8*)&lds[X0_E + q * X0_KS + ((n * 4 + wave + dyn) * 18 + (m + dxn)) * 8];
            __builtin_amdgcn_s_setprio(1);
#pragma unroll
            for (int mi = 0; mi < 4; ++mi)
#pragma unroll
                for (int n = 0; n < 4; ++n)
                    acc[mi][n] = __builtin_amdgcn_mfma_f32_16x16x32_bf16(Anow[mi], Bnow[n], acc[mi][n], 0, 0, 0);
            __builtin_amdgcn_s_setprio(0);
#pragma unroll
            for (int mi = 0; mi < 4; ++mi) Anow[mi] = Anext[mi];
#pragma unroll
            for (int n = 0; n < 4; ++n) Bnow[n] = Bnext[n];
        }
        // epilogue: relu (+mask on edge) -> h1, packed b64 stores
        if (!edge) {
#pragma unroll
            for (int mi = 0; mi < 4; ++mi) {
                int ks = mi * 2 + (q >> 1), lo = (q & 1) * 4;
#pragma unroll
                for (int n = 0; n < 4; ++n) {
                    int ptile = n * 4 + wave;
                    floatx4 a = acc[mi][n];
                    *(short4v*)&lds[H1_E + ks * H1_KS + (ptile * 16 + m) * 8 + lo] =
                        pack4(fmaxf(a[0], 0.f), fmaxf(a[1], 0.f), fmaxf(a[2], 0.f), fmaxf(a[3], 0.f));
                }
            }
        } else {
#pragma unroll
            for (int mi = 0; mi < 4; ++mi) {
                int ks = mi * 2 + (q >> 1), lo = (q & 1) * 4;
#pragma unroll
                for (int n = 0; n < 4; ++n) {
                    int ptile = n * 4 + wave;
                    int gy = ty0 - 2 + ptile, gx = tx0 - 2 + m;
                    bool ok = ((uint_t)gy < 512u) && ((uint_t)gx < 512u);
                    floatx4 a = acc[mi][n];
                    float v0 = ok ? fmaxf(a[0], 0.f) : 0.f;
                    float v1 = ok ? fmaxf(a[1], 0.f) : 0.f;
                    float v2 = ok ? fmaxf(a[2], 0.f) : 0.f;
                    float v3 = ok ? fmaxf(a[3], 0.f) : 0.f;
                    *(short4v*)&lds[H1_E + ks * H1_KS + (ptile * 16 + m) * 8 + lo] = pack4(v0, v1, v2, v3);
                }
            }
        }
    }
    __syncthreads();                                   // (2)

    // ================= conv2: h2(14x14x64), A from global =================
    {
        floatx4 acc[4][4];
#pragma unroll
        for (int mi = 0; mi < 4; ++mi) {
            float4 bb = *(const float4*)&B2[mi * 16 + q * 4];
            floatx4 ib = (floatx4){bb.x, bb.y, bb.z, bb.w};
#pragma unroll
            for (int n = 0; n < 4; ++n) acc[mi][n] = ib;
        }
        int hb2[4];
#pragma unroll
        for (int n = 0; n < 4; ++n) {
            int p0 = (n * 4 + wave) * 16 + m;
            int pv = p0 < 196 ? p0 : 195;              // clamp unused tiles in-range
            int py = pv / 14, px = pv - py * 14;
            hb2[n] = py * 16 + px;
        }
        const int wsel = q * 512 + m * 8;
        short8 Anow[4], Bnow[4];
#pragma unroll
        for (int mi = 0; mi < 4; ++mi)
            Anow[mi] = *(const short8*)&W2t[wsel + mi * 128];
        {                                              // s=0: tap0, kh0 -> dy=dx=0
            const int bb0 = H1_E + q * H1_KS;
#pragma unroll
            for (int n = 0; n < 3; ++n)
                Bnow[n] = *(const short8*)&lds[bb0 + hb2[n] * 8];
            if (wave == 0)
                Bnow[3] = *(const short8*)&lds[bb0 + hb2[3] * 8];
        }

#pragma unroll 3
        for (int s = 0; s < 18; ++s) {
            int sn = s < 17 ? s + 1 : 17;
            int tapn = sn >> 1, khn = sn & 1;
            int dyn = tapn / 3, dxn = tapn - dyn * 3;
            short8 Anext[4];
#pragma unroll
            for (int mi = 0; mi < 4; ++mi)
                Anext[mi] = *(const short8*)&W2t[tapn * 4096 + khn * 2048 + wsel + mi * 128];
            short8 Bnext[4];
            const int bbn = H1_E + (khn * 4 + q) * H1_KS + (dyn * 16 + dxn) * 8;
#pragma unroll
            for (int n = 0; n < 3; ++n)
                Bnext[n] = *(const short8*)&lds[bbn + hb2[n] * 8];
            if (wave == 0)                             // ptile 12 only lives on wave 0
                Bnext[3] = *(const short8*)&lds[bbn + hb2[3] * 8];
            __builtin_amdgcn_s_setprio(1);
#pragma unroll
            for (int mi = 0; mi < 4; ++mi) {
#pragma unroll
                for (int n = 0; n < 3; ++n)            // ptile = n*4+wave <= 11 < 13
                    acc[mi][n] = __builtin_amdgcn_mfma_f32_16x16x32_bf16(Anow[mi], Bnow[n], acc[mi][n], 0, 0, 0);
            }
            if (wave == 0) {                           // ptile 12
#pragma unroll
                for (int mi = 0; mi < 4; ++mi)
                    acc[mi][3] = __builtin_amdgcn_mfma_f32_16x16x32_bf16(Anow[mi], Bnow[3], acc[mi][3], 0, 0, 0);
            }
            __builtin_amdgcn_s_setprio(0);
#pragma unroll
            for (int mi = 0; mi < 4; ++mi) Anow[mi] = Anext[mi];
#pragma unroll
            for (int n = 0; n < 4; ++n) Bnow[n] = Bnext[n];
        }
        __syncthreads();                               // (3) h1 reads done before h2 overlay
        // epilogue: relu (+mask on edge) -> h2 channel-major [8][196][8]
#pragma unroll
        for (int n = 0; n < 4; ++n) {
            int ptile = n * 4 + wave;
            if (ptile >= 13) continue;
            int p = ptile * 16 + m;
            bool pok = p < 196;
            bool ok = pok;
            if (edge) {
                int py = p / 14, px = p - py * 14;
                int gy = ty0 - 1 + py, gx = tx0 - 1 + px;
                ok = pok && ((uint_t)gy < 512u) && ((uint_t)gx < 512u);
            }
#pragma unroll
            for (int mi = 0; mi < 4; ++mi) {
                int ks = mi * 2 + (q >> 1), lo = (q & 1) * 4;
                floatx4 a = acc[mi][n];
                float v0 = ok ? fmaxf(a[0], 0.f) : 0.f;
                float v1 = ok ? fmaxf(a[1], 0.f) : 0.f;
                float v2 = ok ? fmaxf(a[2], 0.f) : 0.f;
                float v3 = ok ? fmaxf(a[3], 0.f) : 0.f;
                if (pok)
                    *(short4v*)&lds[H2_E + ks * H2_KQ + p * 8 + lo] = pack4(v0, v1, v2, v3);
            }
        }
    }
    __syncthreads();                                   // (4)

    // ========== conv3 via MFMA: A (selected W3) from global ==========
    {
        floatx4 acc3[9];
#pragma unroll
        for (int n = 0; n < 9; ++n) acc3[n] = (floatx4){0.f, 0.f, 0.f, 0.f};
        int hb3[9];
#pragma unroll
        for (int n = 0; n < 9; ++n) {
            int p = n * 16 + m;
            int py = p / 12, px = p - py * 12;
            hb3[n] = py * 14 + px;
        }
        const ushort_t* W3c = W3T + cls * 9216;
        for (int t2 = wave; t2 < 18; t2 += 4) {
            int tap = t2 >> 1, kh = t2 & 1;
            int dy = tap / 3, dx = tap - dy * 3;
            short8 Aw = *(const short8*)&W3c[t2 * 512 + q * 128 + m * 8];
            const int hbase = H2_E + (kh * 4 + q) * H2_KQ + (dy * 14 + dx) * 8;
            __builtin_amdgcn_s_setprio(1);
#pragma unroll
            for (int n = 0; n < 9; ++n) {
                short8 Bh = *(const short8*)&lds[hbase + hb3[n] * 8];
                acc3[n] = __builtin_amdgcn_mfma_f32_16x16x32_bf16(Aw, Bh, acc3[n], 0, 0, 0);
            }
            __builtin_amdgcn_s_setprio(0);
        }
        float* sf = ldsf + SF_F;
        if (q == 0) {
#pragma unroll
            for (int n = 0; n < 9; ++n) {
                float2 v = {acc3[n][0], acc3[n][1]};
                *(float2*)&sf[wave * 288 + n * 32 + m * 2] = v;
            }
        }
    }
    __syncthreads();                                   // (5)
    if (t < 144) {
        float* sf = ldsf + SF_F;
        int p = t;
        int base = (p >> 4) * 32 + (p & 15) * 2;
        float a0 = sf[base] + sf[288 + base] + sf[576 + base] + sf[864 + base];
        int py = p / 12, px = p - py * 12;
        int gy = ty0 + py, gx = tx0 + px;
        if (gy < 512 && gx < 512) {
            size_t ob = (((size_t)b * 512 + gy) * 512 + gx) * NCH;
            outp[ob] = a0 + B3[cls * NCH + 0];
            if (NCH == 2) {
                float a1 = sf[base + 1] + sf[288 + base + 1] + sf[576 + base + 1] + sf[864 + base + 1];
                outp[ob + 1] = a1 + B3[cls * NCH + 1];
            }
        }
    }
}

extern "C" void kernel_launch(void* const* d_in, const int* in_sizes, int n_in,
                              void* d_out, int out_size, void* d_ws, size_t ws_size,
                              hipStream_t stream) {
    const float* x0  = (const float*)d_in[0];
    const float* f4  = (const float*)d_in[1];
    const float* Wo1 = (const float*)d_in[2];  const float* bo1 = (const float*)d_in[3];
    const float* Wo2 = (const float*)d_in[4];  const float* bo2 = (const float*)d_in[5];
    const float* Wo3 = (const float*)d_in[6];  const float* bo3 = (const float*)d_in[7];
    const float* Ww1 = (const float*)d_in[8];  const float* bw1 = (const float*)d_in[9];
    const float* Ww2 = (const float*)d_in[10]; const float* bw2 = (const float*)d_in[11];
    const float* Ww3 = (const float*)d_in[12]; const float* bw3 = (const float*)d_in[13];
    const float* Wc1 = (const float*)d_in[14]; const float* bc1 = (const float*)d_in[15];
    const float* Wc2 = (const float*)d_in[16]; const float* bc2 = (const float*)d_in[17];
    const float* Wc3 = (const float*)d_in[18]; const float* bc3 = (const float*)d_in[19];

    float* out = (float*)d_out;
    float* offsets_out = out;                      // (4,512,512,2)
    float* weights_out = out + 2097152;            // (4,512,512,1)
    float* pred_out    = out + 3145728;            // (4,3)

    int* cls_ws = (int*)d_ws;                              // 16 B
    ushort_t* wt  = (ushort_t*)((char*)d_ws + 16);         // 110592 ushorts
    ushort_t* w3t = (ushort_t*)((char*)d_ws + 221200);     // 2x27648 ushorts
    float* gap_part = (float*)((char*)d_ws + 331792);      // 4x8x256 floats

    const ushort_t* W1o_t = wt;
    const ushort_t* W2o_t = wt + 18432;
    const ushort_t* W1w_t = wt + 55296;
    const ushort_t* W2w_t = wt + 73728;

    prep_all<<<680, 256, 0, stream>>>(Wo1, Wo2, Ww1, Ww2, Wo3, Ww3, wt, w3t, f4, gap_part);
    cls_finish<<<4, 256, 0, stream>>>(gap_part, Wc1, bc1, Wc2, bc2, Wc3, bc3, pred_out, cls_ws);

    dim3 grid(43 * 43, 4, 2);
    fused_branch<<<grid, 256, 0, stream>>>(x0,
                                           W1o_t, W2o_t, W1w_t, W2w_t, w3t,
                                           bo1, bo2, bw1, bw2,
                                           bo3, bw3,
                                           cls_ws, offsets_out, weights_out);
}

// Round 8
// 565.983 us; speedup vs baseline: 1.2971x; 1.2971x over previous
//
#include <hip/hip_runtime.h>
#include <hip/hip_bf16.h>
#include <math.h>

typedef __attribute__((ext_vector_type(8))) short short8;
typedef __attribute__((ext_vector_type(4))) short short4v;
typedef __attribute__((ext_vector_type(4))) float floatx4;
typedef unsigned short ushort_t;
typedef unsigned int uint_t;

__device__ __forceinline__ ushort_t f2bf(float x) {   // RNE f32 -> bf16
    uint_t u = __float_as_uint(x);
    uint_t r = (u + 0x7fffu + ((u >> 16) & 1u)) >> 16;
    return (ushort_t)r;
}
// HW-packed RNE conversion: 2 floats -> packed bf16x2 (v_cvt_pk_bf16_f32)
__device__ __forceinline__ short4v pack4(float a, float b, float c, float d) {
    union { __hip_bfloat162 h; uint_t u; } lo, hi;
    lo.h = __float22bfloat162_rn(make_float2(a, b));
    hi.h = __float22bfloat162_rn(make_float2(c, d));
    short4v r;
    r[0] = (short)(lo.u & 0xffffu); r[1] = (short)(lo.u >> 16);
    r[2] = (short)(hi.u & 0xffffu); r[3] = (short)(hi.u >> 16);
    return r;
}
__device__ __forceinline__ short8 pack8(float4 v0, float4 v1) {
    short4v lo = pack4(v0.x, v0.y, v0.z, v0.w);
    short4v hi = pack4(v1.x, v1.y, v1.z, v1.w);
    short8 pk;
    pk[0] = lo[0]; pk[1] = lo[1]; pk[2] = lo[2]; pk[3] = lo[3];
    pk[4] = hi[0]; pk[5] = hi[1]; pk[6] = hi[2]; pk[7] = hi[3];
    return pk;
}

// ---------------- prep: weight tiling (W1/W2/W3) + partial GAP -------------
__global__ void prep_all(const float* __restrict__ W1a, const float* __restrict__ W2a,
                         const float* __restrict__ W1b, const float* __restrict__ W2b,
                         const float* __restrict__ W3a, const float* __restrict__ W3b,
                         ushort_t* __restrict__ wt, ushort_t* __restrict__ w3t,
                         const float* __restrict__ f4, float* __restrict__ part) {
    __shared__ float4 red[256];
    int bi = blockIdx.x, t = threadIdx.x;
    if (bi < 432) {
        int i = bi * 256 + t;
        const float* W; int off; int C;
        if (i < 18432)      { W = W1a; off = i;         C = 32; }
        else if (i < 55296) { W = W2a; off = i - 18432; C = 64; }
        else if (i < 73728) { W = W1b; off = i - 55296; C = 32; }
        else                { W = W2b; off = i - 73728; C = 64; }
        int pt = C * 64;
        int tap = off / pt, rem = off - tap * pt;
        int k4 = rem >> 9, rem2 = rem & 511;
        int co = rem2 >> 3, j = rem2 & 7;
        int ci = k4 * 8 + j;
        wt[i] = f2bf(W[(size_t)(tap * C + ci) * 64 + co]);
    } else if (bi < 648) {
        int i = (bi - 432) * 256 + t;          // [0, 55296)
        int branch = i / 27648; int r = i - branch * 27648;
        int cls = r / 9216; int r2 = r - cls * 9216;
        int t2 = r2 >> 9; int r3 = r2 & 511;
        int qq = r3 >> 7; int r4 = r3 & 127;
        int ch = r4 >> 3; int j = r4 & 7;
        int tap = t2 >> 1, kh = t2 & 1;
        int ci = kh * 32 + qq * 8 + j;
        int NCH = branch ? 1 : 2, C3 = branch ? 3 : 6;
        const float* W3 = branch ? W3b : W3a;
        ushort_t v = 0;
        if (ch < NCH) v = f2bf(W3[(size_t)(tap * 64 + ci) * C3 + cls * NCH + ch]);
        w3t[i] = v;
    } else {
        int g = bi - 648;
        int c = g & 7, b = g >> 3;
        int ci4 = t & 63, po = t >> 6;
        const float* f = f4 + ((size_t)b * 1024 + c * 128) * 256;
        float4 s = {0, 0, 0, 0};
        for (int i = 0; i < 32; ++i) {
            float4 v = *(const float4*)&f[(size_t)(i * 4 + po) * 256 + ci4 * 4];
            s.x += v.x; s.y += v.y; s.z += v.z; s.w += v.w;
        }
        red[t] = s;
        __syncthreads();
        if (t < 64) {
            float4 a = red[t], b2 = red[64 + t], c2 = red[128 + t], d2 = red[192 + t];
            float4 gg;
            gg.x = a.x + b2.x + c2.x + d2.x;
            gg.y = a.y + b2.y + c2.y + d2.y;
            gg.z = a.z + b2.z + c2.z + d2.z;
            gg.w = a.w + b2.w + c2.w + d2.w;
            *(float4*)&part[((b * 8 + c) << 8) + t * 4] = gg;
        }
    }
}

// ---------------- classifier finish: MLP + softmax + argmax ----------------
__global__ void cls_finish(const float* __restrict__ part,
                           const float* __restrict__ Wc1, const float* __restrict__ bc1,
                           const float* __restrict__ Wc2, const float* __restrict__ bc2,
                           const float* __restrict__ Wc3, const float* __restrict__ bc3,
                           float* __restrict__ pred_out, int* __restrict__ cls_out) {
    int b = blockIdx.x;
    int t = threadIdx.x;                       // 256 threads
    __shared__ float gap[256];
    __shared__ float z1[128];
    __shared__ float z2[128];
    __shared__ float lg[3];
    float s = 0.f;
    for (int c = 0; c < 8; ++c) s += part[((b * 8 + c) << 8) + t];
    gap[t] = s * (1.0f / 1024.0f);
    __syncthreads();
    if (t < 128) {
        float a = bc1[t];
        for (int i = 0; i < 256; ++i) a += gap[i] * Wc1[i * 128 + t];
        z1[t] = fmaxf(a, 0.f);
    }
    __syncthreads();
    if (t < 128) {
        float a = bc2[t];
        for (int i = 0; i < 128; ++i) a += z1[i] * Wc2[i * 128 + t];
        z2[t] = fmaxf(a, 0.f);
    }
    __syncthreads();
    if (t < 3) {
        float a = bc3[t];
        for (int i = 0; i < 128; ++i) a += z2[i] * Wc3[i * 3 + t];
        lg[t] = a;
    }
    __syncthreads();
    if (t == 0) {
        float m = fmaxf(lg[0], fmaxf(lg[1], lg[2]));
        float e0 = expf(lg[0] - m), e1 = expf(lg[1] - m), e2 = expf(lg[2] - m);
        float ssum = e0 + e1 + e2;
        pred_out[b * 3 + 0] = e0 / ssum;
        pred_out[b * 3 + 1] = e1 / ssum;
        pred_out[b * 3 + 2] = e2 / ssum;
        int idx = 0; float best = lg[0];
        if (lg[1] > best) { best = lg[1]; idx = 1; }
        if (lg[2] > best) { best = lg[2]; idx = 2; }
        cls_out[b] = idx;
    }
}

// ---------------- fused MFMA conv branch (both branches, grid.z) -----------
// R6 structure (432 us, no spill) + s_setprio ONLY (zero register cost).
// R7 lesson: unroll 3 -> 184 MB scratch spill; 1-tap lookahead is the max
// live window this kernel tolerates.
// LDS (ushort):
//   x0  [4 ks x 2600]           : [0, 10400)
//   h1  [8 ks x 2056]           : [10400, 26848)
//   h2  [8 kq][196 px][8 ch]    : [0, 12544)
//   SF  float partials 1152     : floats [6272,7424)
// Total 53696 B -> 3 blocks/CU.
#define X0_E 0
#define X0_KS 2600
#define H1_E 10400
#define H1_KS 2056
#define H2_E 0
#define H2_KQ 1568
#define SF_F 6272
#define LDS_E 26848

__global__ __launch_bounds__(256, 3)
void fused_branch(const float* __restrict__ x0,
                  const ushort_t* __restrict__ W1o_t, const ushort_t* __restrict__ W2o_t,
                  const ushort_t* __restrict__ W1w_t, const ushort_t* __restrict__ W2w_t,
                  const ushort_t* __restrict__ w3t,
                  const float* __restrict__ bo1, const float* __restrict__ bo2,
                  const float* __restrict__ bw1, const float* __restrict__ bw2,
                  const float* __restrict__ bo3, const float* __restrict__ bw3,
                  const int* __restrict__ clsp,
                  float* __restrict__ off_out, float* __restrict__ w_out) {
    __shared__ __align__(16) ushort_t lds[LDS_E];
    float* ldsf = (float*)lds;
    const int t = threadIdx.x;
    const int b = blockIdx.y;
    const int z = blockIdx.z;
    const ushort_t* W1t = z ? W1w_t : W1o_t;
    const ushort_t* W2t = z ? W2w_t : W2o_t;
    const ushort_t* W3T = w3t + z * 27648;
    const float* B1 = z ? bw1 : bo1;
    const float* B2 = z ? bw2 : bo2;
    const float* B3 = z ? bw3 : bo3;
    float* outp = z ? w_out : off_out;
    const int NCH = z ? 1 : 2;

    const int tileY = blockIdx.x / 43, tileX = blockIdx.x - tileY * 43;
    const int ty0 = tileY * 12, tx0 = tileX * 12;
    const bool edge = (tileY == 0) | (tileY == 42) | (tileX == 0) | (tileX == 42);
    const int lane = t & 63, wave = t >> 6;
    const int m = lane & 15, q = lane >> 4;
    const int cls = clsp[b];

    // ---- stage x0 (18x18x32 fp32 -> bf16 [4 ks][324 px][8]), pixel-major --
    for (int pix = t; pix < 324; pix += 256) {
        int py = pix / 18, px = pix - py * 18;
        int gy = ty0 - 3 + py, gx = tx0 - 3 + px;
        ushort_t* dst = &lds[X0_E + pix * 8];
        if (!edge || ((uint_t)gy < 512u && (uint_t)gx < 512u)) {
            const float* xp = x0 + (((size_t)b * 512 + gy) * 512 + gx) * 32;
#pragma unroll
            for (int qq = 0; qq < 4; ++qq)
                *(short8*)&dst[qq * X0_KS] =
                    pack8(*(const float4*)(xp + qq * 8), *(const float4*)(xp + qq * 8 + 4));
        } else {
            short8 zz = {0, 0, 0, 0, 0, 0, 0, 0};
#pragma unroll
            for (int qq = 0; qq < 4; ++qq)
                *(short8*)&dst[qq * X0_KS] = zz;
        }
    }
    __syncthreads();                                   // (1)

    // ================= conv1: h1(16x16x64), A from global =================
    {
        floatx4 acc[4][4];
#pragma unroll
        for (int mi = 0; mi < 4; ++mi) {
            float4 bb = *(const float4*)&B1[mi * 16 + q * 4];   // bias as C-init
            floatx4 ib = (floatx4){bb.x, bb.y, bb.z, bb.w};
#pragma unroll
            for (int n = 0; n < 4; ++n) acc[mi][n] = ib;
        }
        const int wsel = q * 512 + m * 8;
        short8 Anow[4], Bnow[4];
#pragma unroll
        for (int mi = 0; mi < 4; ++mi)
            Anow[mi] = *(const short8*)&W1t[wsel + mi * 128];
#pragma unroll
        for (int n = 0; n < 4; ++n)                    // tap 0: dy=0, dx=0
            Bnow[n] = *(const short8*)&lds[X0_E + q * X0_KS + ((n * 4 + wave) * 18 + m) * 8];

        for (int tap = 0; tap < 9; ++tap) {
            int tn = tap < 8 ? tap + 1 : 8;
            int dyn = tn / 3, dxn = tn - dyn * 3;
            short8 Anext[4];
#pragma unroll
            for (int mi = 0; mi < 4; ++mi)
                Anext[mi] = *(const short8*)&W1t[tn * 2048 + wsel + mi * 128];
            short8 Bnext[4];
#pragma unroll
            for (int n = 0; n < 4; ++n)
                Bnext[n] = *(const short8*)&lds[X0_E + q * X0_KS + ((n * 4 + wave + dyn) * 18 + (m + dxn)) * 8];
            __builtin_amdgcn_s_setprio(1);
#pragma unroll
            for (int mi = 0; mi < 4; ++mi)
#pragma unroll
                for (int n = 0; n < 4; ++n)
                    acc[mi][n] = __builtin_amdgcn_mfma_f32_16x16x32_bf16(Anow[mi], Bnow[n], acc[mi][n], 0, 0, 0);
            __builtin_amdgcn_s_setprio(0);
#pragma unroll
            for (int mi = 0; mi < 4; ++mi) Anow[mi] = Anext[mi];
#pragma unroll
            for (int n = 0; n < 4; ++n) Bnow[n] = Bnext[n];
        }
        // epilogue: relu (+mask on edge) -> h1, packed b64 stores
        if (!edge) {
#pragma unroll
            for (int mi = 0; mi < 4; ++mi) {
                int ks = mi * 2 + (q >> 1), lo = (q & 1) * 4;
#pragma unroll
                for (int n = 0; n < 4; ++n) {
                    int ptile = n * 4 + wave;
                    floatx4 a = acc[mi][n];
                    *(short4v*)&lds[H1_E + ks * H1_KS + (ptile * 16 + m) * 8 + lo] =
                        pack4(fmaxf(a[0], 0.f), fmaxf(a[1], 0.f), fmaxf(a[2], 0.f), fmaxf(a[3], 0.f));
                }
            }
        } else {
#pragma unroll
            for (int mi = 0; mi < 4; ++mi) {
                int ks = mi * 2 + (q >> 1), lo = (q & 1) * 4;
#pragma unroll
                for (int n = 0; n < 4; ++n) {
                    int ptile = n * 4 + wave;
                    int gy = ty0 - 2 + ptile, gx = tx0 - 2 + m;
                    bool ok = ((uint_t)gy < 512u) && ((uint_t)gx < 512u);
                    floatx4 a = acc[mi][n];
                    float v0 = ok ? fmaxf(a[0], 0.f) : 0.f;
                    float v1 = ok ? fmaxf(a[1], 0.f) : 0.f;
                    float v2 = ok ? fmaxf(a[2], 0.f) : 0.f;
                    float v3 = ok ? fmaxf(a[3], 0.f) : 0.f;
                    *(short4v*)&lds[H1_E + ks * H1_KS + (ptile * 16 + m) * 8 + lo] = pack4(v0, v1, v2, v3);
                }
            }
        }
    }
    __syncthreads();                                   // (2)

    // ================= conv2: h2(14x14x64), A from global =================
    {
        floatx4 acc[4][4];
#pragma unroll
        for (int mi = 0; mi < 4; ++mi) {
            float4 bb = *(const float4*)&B2[mi * 16 + q * 4];
            floatx4 ib = (floatx4){bb.x, bb.y, bb.z, bb.w};
#pragma unroll
            for (int n = 0; n < 4; ++n) acc[mi][n] = ib;
        }
        int hb2[4];
#pragma unroll
        for (int n = 0; n < 4; ++n) {
            int p0 = (n * 4 + wave) * 16 + m;
            int pv = p0 < 196 ? p0 : 195;              // clamp unused tiles in-range
            int py = pv / 14, px = pv - py * 14;
            hb2[n] = py * 16 + px;
        }
        const int wsel = q * 512 + m * 8;
        short8 Anow[4], Bnow[4];
#pragma unroll
        for (int mi = 0; mi < 4; ++mi)
            Anow[mi] = *(const short8*)&W2t[wsel + mi * 128];
        {                                              // s=0: tap0, kh0 -> dy=dx=0
            const int bb0 = H1_E + q * H1_KS;
#pragma unroll
            for (int n = 0; n < 3; ++n)
                Bnow[n] = *(const short8*)&lds[bb0 + hb2[n] * 8];
            if (wave == 0)
                Bnow[3] = *(const short8*)&lds[bb0 + hb2[3] * 8];
        }

        for (int s = 0; s < 18; ++s) {
            int sn = s < 17 ? s + 1 : 17;
            int tapn = sn >> 1, khn = sn & 1;
            int dyn = tapn / 3, dxn = tapn - dyn * 3;
            short8 Anext[4];
#pragma unroll
            for (int mi = 0; mi < 4; ++mi)
                Anext[mi] = *(const short8*)&W2t[tapn * 4096 + khn * 2048 + wsel + mi * 128];
            short8 Bnext[4];
            const int bbn = H1_E + (khn * 4 + q) * H1_KS + (dyn * 16 + dxn) * 8;
#pragma unroll
            for (int n = 0; n < 3; ++n)
                Bnext[n] = *(const short8*)&lds[bbn + hb2[n] * 8];
            if (wave == 0)                             // ptile 12 only lives on wave 0
                Bnext[3] = *(const short8*)&lds[bbn + hb2[3] * 8];
            __builtin_amdgcn_s_setprio(1);
#pragma unroll
            for (int mi = 0; mi < 4; ++mi) {
#pragma unroll
                for (int n = 0; n < 3; ++n)            // ptile = n*4+wave <= 11 < 13
                    acc[mi][n] = __builtin_amdgcn_mfma_f32_16x16x32_bf16(Anow[mi], Bnow[n], acc[mi][n], 0, 0, 0);
            }
            if (wave == 0) {                           // ptile 12
#pragma unroll
                for (int mi = 0; mi < 4; ++mi)
                    acc[mi][3] = __builtin_amdgcn_mfma_f32_16x16x32_bf16(Anow[mi], Bnow[3], acc[mi][3], 0, 0, 0);
            }
            __builtin_amdgcn_s_setprio(0);
#pragma unroll
            for (int mi = 0; mi < 4; ++mi) Anow[mi] = Anext[mi];
#pragma unroll
            for (int n = 0; n < 4; ++n) Bnow[n] = Bnext[n];
        }
        __syncthreads();                               // (3) h1 reads done before h2 overlay
        // epilogue: relu (+mask on edge) -> h2 channel-major [8][196][8]
#pragma unroll
        for (int n = 0; n < 4; ++n) {
            int ptile = n * 4 + wave;
            if (ptile >= 13) continue;
            int p = ptile * 16 + m;
            bool pok = p < 196;
            bool ok = pok;
            if (edge) {
                int py = p / 14, px = p - py * 14;
                int gy = ty0 - 1 + py, gx = tx0 - 1 + px;
                ok = pok && ((uint_t)gy < 512u) && ((uint_t)gx < 512u);
            }
#pragma unroll
            for (int mi = 0; mi < 4; ++mi) {
                int ks = mi * 2 + (q >> 1), lo = (q & 1) * 4;
                floatx4 a = acc[mi][n];
                float v0 = ok ? fmaxf(a[0], 0.f) : 0.f;
                float v1 = ok ? fmaxf(a[1], 0.f) : 0.f;
                float v2 = ok ? fmaxf(a[2], 0.f) : 0.f;
                float v3 = ok ? fmaxf(a[3], 0.f) : 0.f;
                if (pok)
                    *(short4v*)&lds[H2_E + ks * H2_KQ + p * 8 + lo] = pack4(v0, v1, v2, v3);
            }
        }
    }
    __syncthreads();                                   // (4)

    // ========== conv3 via MFMA: A (selected W3) from global ==========
    {
        floatx4 acc3[9];
#pragma unroll
        for (int n = 0; n < 9; ++n) acc3[n] = (floatx4){0.f, 0.f, 0.f, 0.f};
        int hb3[9];
#pragma unroll
        for (int n = 0; n < 9; ++n) {
            int p = n * 16 + m;
            int py = p / 12, px = p - py * 12;
            hb3[n] = py * 14 + px;
        }
        const ushort_t* W3c = W3T + cls * 9216;
        for (int t2 = wave; t2 < 18; t2 += 4) {
            int tap = t2 >> 1, kh = t2 & 1;
            int dy = tap / 3, dx = tap - dy * 3;
            short8 Aw = *(const short8*)&W3c[t2 * 512 + q * 128 + m * 8];
            const int hbase = H2_E + (kh * 4 + q) * H2_KQ + (dy * 14 + dx) * 8;
            __builtin_amdgcn_s_setprio(1);
#pragma unroll
            for (int n = 0; n < 9; ++n) {
                short8 Bh = *(const short8*)&lds[hbase + hb3[n] * 8];
                acc3[n] = __builtin_amdgcn_mfma_f32_16x16x32_bf16(Aw, Bh, acc3[n], 0, 0, 0);
            }
            __builtin_amdgcn_s_setprio(0);
        }
        float* sf = ldsf + SF_F;
        if (q == 0) {
#pragma unroll
            for (int n = 0; n < 9; ++n) {
                float2 v = {acc3[n][0], acc3[n][1]};
                *(float2*)&sf[wave * 288 + n * 32 + m * 2] = v;
            }
        }
    }
    __syncthreads();                                   // (5)
    if (t < 144) {
        float* sf = ldsf + SF_F;
        int p = t;
        int base = (p >> 4) * 32 + (p & 15) * 2;
        float a0 = sf[base] + sf[288 + base] + sf[576 + base] + sf[864 + base];
        int py = p / 12, px = p - py * 12;
        int gy = ty0 + py, gx = tx0 + px;
        if (gy < 512 && gx < 512) {
            size_t ob = (((size_t)b * 512 + gy) * 512 + gx) * NCH;
            outp[ob] = a0 + B3[cls * NCH + 0];
            if (NCH == 2) {
                float a1 = sf[base + 1] + sf[288 + base + 1] + sf[576 + base + 1] + sf[864 + base + 1];
                outp[ob + 1] = a1 + B3[cls * NCH + 1];
            }
        }
    }
}

extern "C" void kernel_launch(void* const* d_in, const int* in_sizes, int n_in,
                              void* d_out, int out_size, void* d_ws, size_t ws_size,
                              hipStream_t stream) {
    const float* x0  = (const float*)d_in[0];
    const float* f4  = (const float*)d_in[1];
    const float* Wo1 = (const float*)d_in[2];  const float* bo1 = (const float*)d_in[3];
    const float* Wo2 = (const float*)d_in[4];  const float* bo2 = (const float*)d_in[5];
    const float* Wo3 = (const float*)d_in[6];  const float* bo3 = (const float*)d_in[7];
    const float* Ww1 = (const float*)d_in[8];  const float* bw1 = (const float*)d_in[9];
    const float* Ww2 = (const float*)d_in[10]; const float* bw2 = (const float*)d_in[11];
    const float* Ww3 = (const float*)d_in[12]; const float* bw3 = (const float*)d_in[13];
    const float* Wc1 = (const float*)d_in[14]; const float* bc1 = (const float*)d_in[15];
    const float* Wc2 = (const float*)d_in[16]; const float* bc2 = (const float*)d_in[17];
    const float* Wc3 = (const float*)d_in[18]; const float* bc3 = (const float*)d_in[19];

    float* out = (float*)d_out;
    float* offsets_out = out;                      // (4,512,512,2)
    float* weights_out = out + 2097152;            // (4,512,512,1)
    float* pred_out    = out + 3145728;            // (4,3)

    int* cls_ws = (int*)d_ws;                              // 16 B
    ushort_t* wt  = (ushort_t*)((char*)d_ws + 16);         // 110592 ushorts
    ushort_t* w3t = (ushort_t*)((char*)d_ws + 221200);     // 2x27648 ushorts
    float* gap_part = (float*)((char*)d_ws + 331792);      // 4x8x256 floats

    const ushort_t* W1o_t = wt;
    const ushort_t* W2o_t = wt + 18432;
    const ushort_t* W1w_t = wt + 55296;
    const ushort_t* W2w_t = wt + 73728;

    prep_all<<<680, 256, 0, stream>>>(Wo1, Wo2, Ww1, Ww2, Wo3, Ww3, wt, w3t, f4, gap_part);
    cls_finish<<<4, 256, 0, stream>>>(gap_part, Wc1, bc1, Wc2, bc2, Wc3, bc3, pred_out, cls_ws);

    dim3 grid(43 * 43, 4, 2);
    fused_branch<<<grid, 256, 0, stream>>>(x0,
                                           W1o_t, W2o_t, W1w_t, W2w_t, w3t,
                                           bo1, bo2, bw1, bw2,
                                           bo3, bw3,
                                           cls_ws, offsets_out, weights_out);
}